// Round 7
// baseline (244.063 us; speedup 1.0000x reference)
//
#include <hip/hip_runtime.h>
#include <hip/hip_fp16.h>

#define S_LEN 4096
#define B_N   32
#define H_N   512
#define BH    (B_N * H_N)        // 16384
#define CROWS 64                 // s-rows per fused block
#define NCH   (S_LEN / CROWS)    // 64 chunks per b

typedef __attribute__((ext_vector_type(8))) short bf16x8;
typedef __attribute__((ext_vector_type(4))) float f32x4;
typedef __attribute__((ext_vector_type(4))) unsigned short us4;

__device__ __forceinline__ unsigned short f2bf(float x) {
    union { float f; unsigned u; } c; c.f = x;
    unsigned r = c.u + 0x7fffu + ((c.u >> 16) & 1u);   // RNE
    return (unsigned short)(r >> 16);
}

// async global->LDS, 16B per lane, LDS dest = wave-uniform base + lane*16
__device__ __forceinline__ void gload_lds16(const void* g, void* l) {
    __builtin_amdgcn_global_load_lds(
        (__attribute__((address_space(1))) void*)g,
        (__attribute__((address_space(3))) void*)l, 16, 0, 0);
}

// ---------------- K0: Wk fp32 -> bf16 in MFMA-FRAGMENT order ----------------
__global__ __launch_bounds__(256) void wkfrag_kernel(const float* __restrict__ Wk,
                                                     unsigned short* __restrict__ WbF) {
    int g = blockIdx.x * 256 + threadIdx.x;   // 0..32767 lane-slots
    int lane = g & 63;
    int n    = (g >> 6) & 7;
    int ks   = (g >> 9) & 15;
    int wn   = g >> 13;
    int col = wn * 128 + n * 16 + (lane & 15);
    int k   = ks * 32 + (lane >> 4) * 8;
    const float* src = Wk + (size_t)col * H_N + k;
    float4 v0 = *(const float4*)(src);
    float4 v1 = *(const float4*)(src + 4);
    us4 a = {f2bf(v0.x), f2bf(v0.y), f2bf(v0.z), f2bf(v0.w)};
    us4 b = {f2bf(v1.x), f2bf(v1.y), f2bf(v1.z), f2bf(v1.w)};
    *(us4*)(WbF + (size_t)g * 8)     = a;
    *(us4*)(WbF + (size_t)g * 8 + 4) = b;
}

// ---------------- K1: prep = column sums + bf16 swizzled A-tile store ----------------
// One block per (b, chunk). Reads hs ONCE; writes the tile only if active.
// Tile byte layout == fused kernel's LDS layout (row*1024 + ((kq*8)^((row&7)<<4))).
__global__ __launch_bounds__(256) void prep_kernel(const float* __restrict__ hs,
                                                   float* __restrict__ hsum,
                                                   unsigned short* __restrict__ AT,
                                                   const int* __restrict__ lengths) {
    int blk = blockIdx.x;                 // chunk*32 + b  (matches fused blockIdx)
    int b = blk & 31, chunk = blk >> 5;
    int s0 = chunk * CROWS;
    bool active = (s0 < lengths[b]);
    int t = threadIdx.x;
    int kq = t & 127, r0 = t >> 7;        // float4-quad in row; row parity
    const float* hb = hs + ((size_t)s0 * B_N + b) * H_N + kq * 4;
    char* tile = (char*)(AT + (size_t)blk * (CROWS * H_N));
    float4 sum = {0.f, 0.f, 0.f, 0.f};
    #pragma unroll 8
    for (int j = 0; j < 32; ++j) {
        int row = r0 + 2 * j;
        float4 v = *(const float4*)(hb + (size_t)row * BH);
        sum.x += v.x; sum.y += v.y; sum.z += v.z; sum.w += v.w;
        if (active) {
            us4 u = {f2bf(v.x), f2bf(v.y), f2bf(v.z), f2bf(v.w)};
            *(us4*)(tile + row * 1024 + ((kq * 8) ^ ((row & 7) << 4))) = u;
        }
    }
    int col = b * H_N + kq * 4;
    atomicAdd(&hsum[col],     sum.x);
    atomicAdd(&hsum[col + 1], sum.y);
    atomicAdd(&hsum[col + 2], sum.z);
    atomicAdd(&hsum[col + 3], sum.w);
}

// ---------------- K2: q[b,h] ----------------
__global__ __launch_bounds__(256) void q_kernel(const float* __restrict__ hsum,
                                                const float* __restrict__ Wq,
                                                const float* __restrict__ bq,
                                                float* __restrict__ q) {
    int b = blockIdx.x, t = threadIdx.x;
    __shared__ float hrow[H_N];
    hrow[t]       = hsum[b * H_N + t]       * (1.f / S_LEN);
    hrow[t + 256] = hsum[b * H_N + t + 256] * (1.f / S_LEN);
    __syncthreads();
    for (int h = t; h < H_N; h += 256) {
        const float* wrow = Wq + (size_t)h * H_N;
        float acc = 0.f;
        #pragma unroll 8
        for (int k = 0; k < H_N; ++k) acc = fmaf(hrow[k], wrow[k], acc);
        q[b * H_N + h] = acc + bq[h];
    }
}

// ---------------- K3: fused key GEMM + tanh + scores + softmax + PV partials ----------------
// A-tile arrives pre-converted, pre-swizzled: staged via global_load_lds (byte copy).
__global__ __launch_bounds__(512, 4) void fused_kernel(
    const unsigned short* __restrict__ AT, const unsigned short* __restrict__ WbF,
    const float* __restrict__ bk, const float* __restrict__ qv,
    const int* __restrict__ lengths,
    float* __restrict__ pm, float* __restrict__ pl, float* __restrict__ po)
{
    int blk = blockIdx.x;
    int b = blk & 31;
    int chunk = blk >> 5;
    int s0 = chunk * CROWS;
    int t = threadIdx.x;

    int len = lengths[b];
    if (s0 >= len) {                       // fully masked: contributes exactly 0
        po[((size_t)b * NCH + chunk) * H_N + t] = 0.f;
        if (t == 0) { pm[b * NCH + chunk] = -1e30f; pl[b * NCH + chunk] = 0.f; }
        return;
    }

    int lane = t & 63, wv = t >> 6;
    int l15 = lane & 15, lg = lane >> 4;
    int wm = wv >> 2, wn = wv & 3;

    __shared__ __align__(16) unsigned short A_s[CROWS * H_N]; // 64 KB; opart aliases later
    __shared__ float q_s[H_N];
    __shared__ float bk_s[H_N];
    __shared__ float scp[4][CROWS];
    __shared__ float score_s[CROWS];
    __shared__ float p_s[CROWS];

    // ---- stage A: byte-verbatim async copy of the pre-swizzled tile ----
    const char* tsrc = (const char*)(AT + (size_t)blk * (CROWS * H_N));
    {
        int wbase = wv * 8192;
        #pragma unroll
        for (int j = 0; j < 8; ++j) {
            int off = wbase + j * 1024;
            gload_lds16(tsrc + off + lane * 16, (char*)A_s + off);
        }
    }
    q_s[t]  = qv[b * H_N + t];    // 512 threads cover 512 entries
    bk_s[t] = bk[t];
    __syncthreads();              // drains vmcnt incl. global_load_lds

    // ---- K-loop: 16 steps of k32; B from fragment-ordered WbF (coalesced) ----
    const unsigned short* wbF = WbF + (size_t)wn * 65536 + lane * 8;
    const char* Ab = (const char*)A_s + (wm * 32 + l15) * 1024;
    int axor = (l15 & 7) << 4;

    f32x4 acc[2][8];
    #pragma unroll
    for (int m = 0; m < 2; ++m)
        #pragma unroll
        for (int n = 0; n < 8; ++n) acc[m][n] = (f32x4){0.f, 0.f, 0.f, 0.f};

    #pragma unroll
    for (int ks = 0; ks < 16; ++ks) {
        const unsigned short* wk = wbF + ks * 4096;
        bf16x8 b0 = *(const bf16x8*)(wk + 0 * 512);
        bf16x8 b1 = *(const bf16x8*)(wk + 1 * 512);
        bf16x8 b2 = *(const bf16x8*)(wk + 2 * 512);
        bf16x8 b3 = *(const bf16x8*)(wk + 3 * 512);
        bf16x8 b4 = *(const bf16x8*)(wk + 4 * 512);
        bf16x8 b5 = *(const bf16x8*)(wk + 5 * 512);
        bf16x8 b6 = *(const bf16x8*)(wk + 6 * 512);
        bf16x8 b7 = *(const bf16x8*)(wk + 7 * 512);
        int off = (ks * 64 + lg * 16) ^ axor;
        bf16x8 a0 = *(const bf16x8*)(Ab + off);
        bf16x8 a1 = *(const bf16x8*)(Ab + 16 * 1024 + off);
        __builtin_amdgcn_s_setprio(1);
        acc[0][0] = __builtin_amdgcn_mfma_f32_16x16x32_bf16(a0, b0, acc[0][0], 0, 0, 0);
        acc[1][0] = __builtin_amdgcn_mfma_f32_16x16x32_bf16(a1, b0, acc[1][0], 0, 0, 0);
        acc[0][1] = __builtin_amdgcn_mfma_f32_16x16x32_bf16(a0, b1, acc[0][1], 0, 0, 0);
        acc[1][1] = __builtin_amdgcn_mfma_f32_16x16x32_bf16(a1, b1, acc[1][1], 0, 0, 0);
        acc[0][2] = __builtin_amdgcn_mfma_f32_16x16x32_bf16(a0, b2, acc[0][2], 0, 0, 0);
        acc[1][2] = __builtin_amdgcn_mfma_f32_16x16x32_bf16(a1, b2, acc[1][2], 0, 0, 0);
        acc[0][3] = __builtin_amdgcn_mfma_f32_16x16x32_bf16(a0, b3, acc[0][3], 0, 0, 0);
        acc[1][3] = __builtin_amdgcn_mfma_f32_16x16x32_bf16(a1, b3, acc[1][3], 0, 0, 0);
        acc[0][4] = __builtin_amdgcn_mfma_f32_16x16x32_bf16(a0, b4, acc[0][4], 0, 0, 0);
        acc[1][4] = __builtin_amdgcn_mfma_f32_16x16x32_bf16(a1, b4, acc[1][4], 0, 0, 0);
        acc[0][5] = __builtin_amdgcn_mfma_f32_16x16x32_bf16(a0, b5, acc[0][5], 0, 0, 0);
        acc[1][5] = __builtin_amdgcn_mfma_f32_16x16x32_bf16(a1, b5, acc[1][5], 0, 0, 0);
        acc[0][6] = __builtin_amdgcn_mfma_f32_16x16x32_bf16(a0, b6, acc[0][6], 0, 0, 0);
        acc[1][6] = __builtin_amdgcn_mfma_f32_16x16x32_bf16(a1, b6, acc[1][6], 0, 0, 0);
        acc[0][7] = __builtin_amdgcn_mfma_f32_16x16x32_bf16(a0, b7, acc[0][7], 0, 0, 0);
        acc[1][7] = __builtin_amdgcn_mfma_f32_16x16x32_bf16(a1, b7, acc[1][7], 0, 0, 0);
        __builtin_amdgcn_s_setprio(0);
    }

    // ---- epilogue: bias + tanh (in place) + score partials ----
    float sp[2][4] = {{0,0,0,0},{0,0,0,0}};
    #pragma unroll
    for (int m = 0; m < 2; ++m)
        #pragma unroll
        for (int n = 0; n < 8; ++n) {
            int c = wn * 128 + n * 16 + l15;
            float bkv = bk_s[c], qc = q_s[c];
            #pragma unroll
            for (int i = 0; i < 4; ++i) {
                float z = acc[m][n][i] + bkv;
                float e = __expf(2.f * z);
                float kv = 1.f - 2.f / (e + 1.f);     // tanh
                acc[m][n][i] = kv;                    // key kept in regs
                sp[m][i] = fmaf(kv, qc, sp[m][i]);
            }
        }
    #pragma unroll
    for (int m = 0; m < 2; ++m)
        #pragma unroll
        for (int i = 0; i < 4; ++i) {
            float v = sp[m][i];
            v += __shfl_xor(v, 1); v += __shfl_xor(v, 2);
            v += __shfl_xor(v, 4); v += __shfl_xor(v, 8);
            if (l15 == 0) scp[wn][wm * 32 + m * 16 + lg * 4 + i] = v;
        }
    __syncthreads();

    // ---- softmax over the 64 rows ----
    if (t < CROWS) {
        float sc = scp[0][t] + scp[1][t] + scp[2][t] + scp[3][t];
        if (s0 + t >= len) sc -= 10000.f;
        score_s[t] = sc;
    }
    __syncthreads();
    float mx = -1e30f;
    #pragma unroll 8
    for (int r = 0; r < CROWS; ++r) mx = fmaxf(mx, score_s[r]);
    if (t < CROWS) p_s[t] = __expf(score_s[t] - mx);
    __syncthreads();

    // ---- PV from register-resident key; partials into LDS aliased over A_s ----
    float* opart = (float*)A_s;               // [8][H_N] = 16 KB
    float o8[8] = {0,0,0,0,0,0,0,0};
    #pragma unroll
    for (int m = 0; m < 2; ++m)
        #pragma unroll
        for (int i = 0; i < 4; ++i) {
            float p = p_s[wm * 32 + m * 16 + lg * 4 + i];
            #pragma unroll
            for (int n = 0; n < 8; ++n) o8[n] = fmaf(p, acc[m][n][i], o8[n]);
        }
    int slice = wm * 4 + lg;
    #pragma unroll
    for (int n = 0; n < 8; ++n) opart[slice * H_N + wn * 128 + n * 16 + l15] = o8[n];
    __syncthreads();

    {
        float o = 0.f;
        #pragma unroll
        for (int s = 0; s < 8; ++s) o += opart[s * H_N + t];
        po[((size_t)b * NCH + chunk) * H_N + t] = o;
    }
    if (t == 0) {
        float l = 0.f;
        #pragma unroll 8
        for (int r = 0; r < CROWS; ++r) l += p_s[r];
        pm[b * NCH + chunk] = mx;
        pl[b * NCH + chunk] = l;
    }
}

// ---------------- K4: combine chunk partials ----------------
__global__ __launch_bounds__(256) void combine_kernel(
    const float* __restrict__ pm, const float* __restrict__ pl,
    const float* __restrict__ po, float* __restrict__ out)
{
    int b = blockIdx.x, t = threadIdx.x;
    float M = -1e30f;
    for (int c = 0; c < NCH; ++c) M = fmaxf(M, pm[b * NCH + c]);
    float den = 0.f, n0 = 0.f, n1 = 0.f;
    for (int c = 0; c < NCH; ++c) {
        float w = __expf(pm[b * NCH + c] - M);
        den = fmaf(w, pl[b * NCH + c], den);
        const float* op = po + (size_t)(b * NCH + c) * H_N;
        n0 = fmaf(w, op[t], n0);
        n1 = fmaf(w, op[t + 256], n1);
    }
    out[b * H_N + t]       = n0 / den;
    out[b * H_N + t + 256] = n1 / den;
}

extern "C" void kernel_launch(void* const* d_in, const int* in_sizes, int n_in,
                              void* d_out, int out_size, void* d_ws, size_t ws_size,
                              hipStream_t stream) {
    const float* hs      = (const float*)d_in[0];
    const float* Wq      = (const float*)d_in[1];
    const float* bq      = (const float*)d_in[2];
    const float* Wk      = (const float*)d_in[3];
    const float* bk      = (const float*)d_in[4];
    const int*   lengths = (const int*)d_in[5];
    float* out = (float*)d_out;

    float* ws   = (float*)d_ws;
    float* hsum = ws;                              // 16384 floats
    float* qv   = hsum + BH;                       // 16384
    float* pm   = qv + BH;                         // 2048
    float* pl   = pm + B_N * NCH;                  // 2048
    float* po   = pl + B_N * NCH;                  // 1048576 floats
    unsigned short* WbF = (unsigned short*)(po + (size_t)B_N * NCH * H_N);   // 512 KB
    unsigned short* AT  = WbF + (size_t)H_N * H_N;                           // 128 MiB bf16 tiles

    hipMemsetAsync(hsum, 0, BH * sizeof(float), stream);
    hipLaunchKernelGGL(wkfrag_kernel, dim3(128), dim3(256), 0, stream, Wk, WbF);
    hipLaunchKernelGGL(prep_kernel, dim3(B_N * NCH), dim3(256), 0, stream, hs, hsum, AT, lengths);
    hipLaunchKernelGGL(q_kernel, dim3(B_N), dim3(256), 0, stream, hsum, Wq, bq, qv);
    hipLaunchKernelGGL(fused_kernel, dim3(B_N * NCH), dim3(512), 0, stream,
                       AT, WbF, bk, qv, lengths, pm, pl, po);
    hipLaunchKernelGGL(combine_kernel, dim3(B_N), dim3(256), 0, stream, pm, pl, po, out);
}

// Round 8
// 236.706 us; speedup vs baseline: 1.0311x; 1.0311x over previous
//
#include <hip/hip_runtime.h>
#include <hip/hip_fp16.h>

#define S_LEN 4096
#define B_N   32
#define H_N   512
#define BH    (B_N * H_N)        // 16384
#define CROWS 64                 // s-rows per fused block
#define NCH   (S_LEN / CROWS)    // 64 chunks per b

typedef __attribute__((ext_vector_type(8))) short bf16x8;
typedef __attribute__((ext_vector_type(4))) float f32x4;
typedef __attribute__((ext_vector_type(4))) unsigned short us4;

__device__ __forceinline__ unsigned short f2bf(float x) {
    union { float f; unsigned u; } c; c.f = x;
    unsigned r = c.u + 0x7fffu + ((c.u >> 16) & 1u);   // RNE
    return (unsigned short)(r >> 16);
}

// ---------------- K0: Wk fp32 -> bf16 in MFMA-FRAGMENT order ----------------
// WbF element index = ((wn*16 + ks)*8 + n)*512 + lane*8 + j
// maps to Wk[col][k], col = wn*128 + n*16 + (lane&15), k = ks*32 + (lane>>4)*8 + j.
// A wave's B-load becomes base + lane*16B -> 1KB contiguous per instruction.
__global__ __launch_bounds__(256) void wkfrag_kernel(const float* __restrict__ Wk,
                                                     unsigned short* __restrict__ WbF) {
    int g = blockIdx.x * 256 + threadIdx.x;   // 0..32767 lane-slots
    int lane = g & 63;
    int n    = (g >> 6) & 7;
    int ks   = (g >> 9) & 15;
    int wn   = g >> 13;
    int col = wn * 128 + n * 16 + (lane & 15);
    int k   = ks * 32 + (lane >> 4) * 8;
    const float* src = Wk + (size_t)col * H_N + k;
    float4 v0 = *(const float4*)(src);
    float4 v1 = *(const float4*)(src + 4);
    us4 a = {f2bf(v0.x), f2bf(v0.y), f2bf(v0.z), f2bf(v0.w)};
    us4 b = {f2bf(v1.x), f2bf(v1.y), f2bf(v1.z), f2bf(v1.w)};
    *(us4*)(WbF + (size_t)g * 8)     = a;
    *(us4*)(WbF + (size_t)g * 8 + 4) = b;
}

// ---------------- K1: hsum[b,h] = sum_s hs[s,b,h] ----------------
__global__ __launch_bounds__(256) void hsum_kernel(const float* __restrict__ hs,
                                                   float* __restrict__ hsum) {
    int col = (blockIdx.x * 256 + threadIdx.x) * 4;
    size_t s0 = (size_t)blockIdx.y * 128;
    float4 acc = {0.f, 0.f, 0.f, 0.f};
    #pragma unroll 8
    for (int i = 0; i < 128; ++i) {
        float4 v = *(const float4*)(hs + (s0 + i) * BH + col);
        acc.x += v.x; acc.y += v.y; acc.z += v.z; acc.w += v.w;
    }
    atomicAdd(&hsum[col],     acc.x);
    atomicAdd(&hsum[col + 1], acc.y);
    atomicAdd(&hsum[col + 2], acc.z);
    atomicAdd(&hsum[col + 3], acc.w);
}

// ---------------- K2: q[b,h] — coalesced: lanes split k, shuffle-reduce ----------------
// Wave reads Wq[h, lane*8 .. lane*8+7] -> 2KB contiguous per load pair.
__global__ __launch_bounds__(512) void q_kernel(const float* __restrict__ hsum,
                                                const float* __restrict__ Wq,
                                                const float* __restrict__ bq,
                                                float* __restrict__ q) {
    int b = blockIdx.x, t = threadIdx.x;
    int lane = t & 63, wv = t >> 6;         // 8 waves
    __shared__ float hrow[H_N];
    hrow[t] = hsum[b * H_N + t] * (1.f / S_LEN);
    __syncthreads();
    float h0 = hrow[lane * 8 + 0], h1 = hrow[lane * 8 + 1];
    float h2 = hrow[lane * 8 + 2], h3 = hrow[lane * 8 + 3];
    float h4 = hrow[lane * 8 + 4], h5 = hrow[lane * 8 + 5];
    float h6 = hrow[lane * 8 + 6], h7 = hrow[lane * 8 + 7];
    for (int i = 0; i < 64; ++i) {          // each wave: 64 output h's
        int h = wv * 64 + i;
        const float* wrow = Wq + (size_t)h * H_N + lane * 8;
        float4 w0 = *(const float4*)(wrow);
        float4 w1 = *(const float4*)(wrow + 4);
        float acc = h0 * w0.x + h1 * w0.y + h2 * w0.z + h3 * w0.w
                  + h4 * w1.x + h5 * w1.y + h6 * w1.z + h7 * w1.w;
        acc += __shfl_xor(acc, 1);  acc += __shfl_xor(acc, 2);
        acc += __shfl_xor(acc, 4);  acc += __shfl_xor(acc, 8);
        acc += __shfl_xor(acc, 16); acc += __shfl_xor(acc, 32);
        if (lane == 0) q[b * H_N + h] = acc + bq[h];
    }
}

// ---------------- K3: fused key GEMM + tanh + scores + softmax + PV partials ----------------
// 512 thr = 8 waves (2 wm x 4 wn), 64 rows x 512 cols per block.
// Fully-masked chunks (s0 >= len) early-exit (exp underflows to exactly 0).
// B loads coalesced via fragment-ordered WbF. A staged from hs with swizzle.
__global__ __launch_bounds__(512, 4) void fused_kernel(
    const float* __restrict__ hs, const unsigned short* __restrict__ WbF,
    const float* __restrict__ bk, const float* __restrict__ qv,
    const int* __restrict__ lengths,
    float* __restrict__ pm, float* __restrict__ pl, float* __restrict__ po)
{
    int blk = blockIdx.x;
    int b = blk & 31;
    int chunk = blk >> 5;
    int s0 = chunk * CROWS;
    int t = threadIdx.x;

    int len = lengths[b];
    if (s0 >= len) {                       // fully masked: contributes exactly 0
        po[((size_t)b * NCH + chunk) * H_N + t] = 0.f;
        if (t == 0) { pm[b * NCH + chunk] = -1e30f; pl[b * NCH + chunk] = 0.f; }
        return;
    }

    int lane = t & 63, wv = t >> 6;
    int l15 = lane & 15, lg = lane >> 4;
    int wm = wv >> 2, wn = wv & 3;

    __shared__ __align__(16) unsigned short A_s[CROWS * H_N]; // 64 KB; opart aliases later
    __shared__ float q_s[H_N];
    __shared__ float bk_s[H_N];
    __shared__ float scp[4][CROWS];
    __shared__ float score_s[CROWS];
    __shared__ float p_s[CROWS];

    q_s[t]  = qv[b * H_N + t];    // 512 threads cover 512 entries
    bk_s[t] = bk[t];

    // ---- stage A: 64 rows x 512 cols fp32 -> bf16, swizzle byte ^= (row&7)<<4 ----
    const float* hb = hs + ((size_t)s0 * B_N + b) * H_N;   // row stride BH floats
    int kq  = t & 127;
    int r0l = t >> 7;
    #pragma unroll 8
    for (int j = 0; j < 16; ++j) {
        int row = r0l + 4 * j;
        float4 v = *(const float4*)(hb + (size_t)row * BH + kq * 4);
        us4 u = {f2bf(v.x), f2bf(v.y), f2bf(v.z), f2bf(v.w)};
        *(us4*)((char*)A_s + row * 1024 + ((kq * 8) ^ ((row & 7) << 4))) = u;
    }
    __syncthreads();

    // ---- K-loop: 16 steps of k32; B from fragment-ordered WbF (coalesced) ----
    const unsigned short* wbF = WbF + (size_t)wn * 65536 + lane * 8;
    const char* Ab = (const char*)A_s + (wm * 32 + l15) * 1024;
    int axor = (l15 & 7) << 4;

    f32x4 acc[2][8];
    #pragma unroll
    for (int m = 0; m < 2; ++m)
        #pragma unroll
        for (int n = 0; n < 8; ++n) acc[m][n] = (f32x4){0.f, 0.f, 0.f, 0.f};

    #pragma unroll
    for (int ks = 0; ks < 16; ++ks) {
        const unsigned short* wk = wbF + ks * 4096;
        bf16x8 b0 = *(const bf16x8*)(wk + 0 * 512);
        bf16x8 b1 = *(const bf16x8*)(wk + 1 * 512);
        bf16x8 b2 = *(const bf16x8*)(wk + 2 * 512);
        bf16x8 b3 = *(const bf16x8*)(wk + 3 * 512);
        bf16x8 b4 = *(const bf16x8*)(wk + 4 * 512);
        bf16x8 b5 = *(const bf16x8*)(wk + 5 * 512);
        bf16x8 b6 = *(const bf16x8*)(wk + 6 * 512);
        bf16x8 b7 = *(const bf16x8*)(wk + 7 * 512);
        int off = (ks * 64 + lg * 16) ^ axor;
        bf16x8 a0 = *(const bf16x8*)(Ab + off);
        bf16x8 a1 = *(const bf16x8*)(Ab + 16 * 1024 + off);
        __builtin_amdgcn_s_setprio(1);
        acc[0][0] = __builtin_amdgcn_mfma_f32_16x16x32_bf16(a0, b0, acc[0][0], 0, 0, 0);
        acc[1][0] = __builtin_amdgcn_mfma_f32_16x16x32_bf16(a1, b0, acc[1][0], 0, 0, 0);
        acc[0][1] = __builtin_amdgcn_mfma_f32_16x16x32_bf16(a0, b1, acc[0][1], 0, 0, 0);
        acc[1][1] = __builtin_amdgcn_mfma_f32_16x16x32_bf16(a1, b1, acc[1][1], 0, 0, 0);
        acc[0][2] = __builtin_amdgcn_mfma_f32_16x16x32_bf16(a0, b2, acc[0][2], 0, 0, 0);
        acc[1][2] = __builtin_amdgcn_mfma_f32_16x16x32_bf16(a1, b2, acc[1][2], 0, 0, 0);
        acc[0][3] = __builtin_amdgcn_mfma_f32_16x16x32_bf16(a0, b3, acc[0][3], 0, 0, 0);
        acc[1][3] = __builtin_amdgcn_mfma_f32_16x16x32_bf16(a1, b3, acc[1][3], 0, 0, 0);
        acc[0][4] = __builtin_amdgcn_mfma_f32_16x16x32_bf16(a0, b4, acc[0][4], 0, 0, 0);
        acc[1][4] = __builtin_amdgcn_mfma_f32_16x16x32_bf16(a1, b4, acc[1][4], 0, 0, 0);
        acc[0][5] = __builtin_amdgcn_mfma_f32_16x16x32_bf16(a0, b5, acc[0][5], 0, 0, 0);
        acc[1][5] = __builtin_amdgcn_mfma_f32_16x16x32_bf16(a1, b5, acc[1][5], 0, 0, 0);
        acc[0][6] = __builtin_amdgcn_mfma_f32_16x16x32_bf16(a0, b6, acc[0][6], 0, 0, 0);
        acc[1][6] = __builtin_amdgcn_mfma_f32_16x16x32_bf16(a1, b6, acc[1][6], 0, 0, 0);
        acc[0][7] = __builtin_amdgcn_mfma_f32_16x16x32_bf16(a0, b7, acc[0][7], 0, 0, 0);
        acc[1][7] = __builtin_amdgcn_mfma_f32_16x16x32_bf16(a1, b7, acc[1][7], 0, 0, 0);
        __builtin_amdgcn_s_setprio(0);
    }

    // ---- epilogue: bias + tanh (in place) + score partials ----
    // C/D: lane holds D[row = wm*32 + m*16 + lg*4 + i][col = wn*128 + n*16 + l15]
    float sp[2][4] = {{0,0,0,0},{0,0,0,0}};
    #pragma unroll
    for (int m = 0; m < 2; ++m)
        #pragma unroll
        for (int n = 0; n < 8; ++n) {
            int c = wn * 128 + n * 16 + l15;
            float bkv = bk_s[c], qc = q_s[c];
            #pragma unroll
            for (int i = 0; i < 4; ++i) {
                float z = acc[m][n][i] + bkv;
                float e = __expf(2.f * z);
                float kv = 1.f - 2.f / (e + 1.f);     // tanh
                acc[m][n][i] = kv;                    // key kept in regs
                sp[m][i] = fmaf(kv, qc, sp[m][i]);
            }
        }
    #pragma unroll
    for (int m = 0; m < 2; ++m)
        #pragma unroll
        for (int i = 0; i < 4; ++i) {
            float v = sp[m][i];
            v += __shfl_xor(v, 1); v += __shfl_xor(v, 2);
            v += __shfl_xor(v, 4); v += __shfl_xor(v, 8);
            if (l15 == 0) scp[wn][wm * 32 + m * 16 + lg * 4 + i] = v;
        }
    __syncthreads();

    // ---- softmax over the 64 rows ----
    if (t < CROWS) {
        float sc = scp[0][t] + scp[1][t] + scp[2][t] + scp[3][t];
        if (s0 + t >= len) sc -= 10000.f;
        score_s[t] = sc;
    }
    __syncthreads();
    float mx = -1e30f;
    #pragma unroll 8
    for (int r = 0; r < CROWS; ++r) mx = fmaxf(mx, score_s[r]);
    if (t < CROWS) p_s[t] = __expf(score_s[t] - mx);
    __syncthreads();

    // ---- PV from register-resident key; partials into LDS aliased over A_s ----
    float* opart = (float*)A_s;               // [8][H_N] = 16 KB
    float o8[8] = {0,0,0,0,0,0,0,0};
    #pragma unroll
    for (int m = 0; m < 2; ++m)
        #pragma unroll
        for (int i = 0; i < 4; ++i) {
            float p = p_s[wm * 32 + m * 16 + lg * 4 + i];
            #pragma unroll
            for (int n = 0; n < 8; ++n) o8[n] = fmaf(p, acc[m][n][i], o8[n]);
        }
    int slice = wm * 4 + lg;
    #pragma unroll
    for (int n = 0; n < 8; ++n) opart[slice * H_N + wn * 128 + n * 16 + l15] = o8[n];
    __syncthreads();

    {
        float o = 0.f;
        #pragma unroll
        for (int s = 0; s < 8; ++s) o += opart[s * H_N + t];
        po[((size_t)b * NCH + chunk) * H_N + t] = o;
    }
    if (t == 0) {
        float l = 0.f;
        #pragma unroll 8
        for (int r = 0; r < CROWS; ++r) l += p_s[r];
        pm[b * NCH + chunk] = mx;
        pl[b * NCH + chunk] = l;
    }
}

// ---------------- K4: combine chunk partials ----------------
__global__ __launch_bounds__(256) void combine_kernel(
    const float* __restrict__ pm, const float* __restrict__ pl,
    const float* __restrict__ po, float* __restrict__ out)
{
    int b = blockIdx.x, t = threadIdx.x;
    float M = -1e30f;
    for (int c = 0; c < NCH; ++c) M = fmaxf(M, pm[b * NCH + c]);
    float den = 0.f, n0 = 0.f, n1 = 0.f;
    for (int c = 0; c < NCH; ++c) {
        float w = __expf(pm[b * NCH + c] - M);
        if (w > 0.f) {
            den = fmaf(w, pl[b * NCH + c], den);
            const float* op = po + (size_t)(b * NCH + c) * H_N;
            n0 = fmaf(w, op[t], n0);
            n1 = fmaf(w, op[t + 256], n1);
        }
    }
    out[b * H_N + t]       = n0 / den;
    out[b * H_N + t + 256] = n1 / den;
}

extern "C" void kernel_launch(void* const* d_in, const int* in_sizes, int n_in,
                              void* d_out, int out_size, void* d_ws, size_t ws_size,
                              hipStream_t stream) {
    const float* hs      = (const float*)d_in[0];
    const float* Wq      = (const float*)d_in[1];
    const float* bq      = (const float*)d_in[2];
    const float* Wk      = (const float*)d_in[3];
    const float* bk      = (const float*)d_in[4];
    const int*   lengths = (const int*)d_in[5];
    float* out = (float*)d_out;

    float* ws   = (float*)d_ws;
    float* hsum = ws;                              // 16384 floats
    float* qv   = hsum + BH;                       // 16384
    float* pm   = qv + BH;                         // 2048
    float* pl   = pm + B_N * NCH;                  // 2048
    float* po   = pl + B_N * NCH;                  // 1048576 floats
    unsigned short* WbF = (unsigned short*)(po + (size_t)B_N * NCH * H_N); // 512 KB

    hipMemsetAsync(hsum, 0, BH * sizeof(float), stream);
    hipLaunchKernelGGL(wkfrag_kernel, dim3(128), dim3(256), 0, stream, Wk, WbF);
    hipLaunchKernelGGL(hsum_kernel, dim3(BH / 1024, S_LEN / 128), dim3(256), 0, stream, hs, hsum);
    hipLaunchKernelGGL(q_kernel, dim3(B_N), dim3(512), 0, stream, hsum, Wq, bq, qv);
    hipLaunchKernelGGL(fused_kernel, dim3(B_N * NCH), dim3(512), 0, stream,
                       hs, WbF, bk, qv, lengths, pm, pl, po);
    hipLaunchKernelGGL(combine_kernel, dim3(B_N), dim3(256), 0, stream, pm, pl, po, out);
}